// Round 5
// baseline (276.412 us; speedup 1.0000x reference)
//
#include <hip/hip_runtime.h>
#include <hip/hip_bf16.h>

// Problem constants
#define NB 32          // batch
#define NG 32          // max gts
#define NC 80          // classes
#define NTOT 8400      // 6400 + 1600 + 400
#define CH 144
#define BN (NB * NTOT)            // 268800 anchors total

#define TILES_PER_B 132           // 100 (l0) + 25 (l1) + 7 (l2, last partial)
#define NBLK1 (NB * TILES_PER_B)  // 4224
#define NBLKN 33                  // ceil(NTOT/256)
#define NBLK3 (NBLKN * NB)        // 1056

struct AInfo {
    const float* base;  // p[lvl] + b*144*hw  (channel-major)
    int hw;
    int off;
    float cx, cy, stride;
};

__device__ __forceinline__ AInfo anchor_info(int n, int b, const float* p0, const float* p1, const float* p2) {
    AInfo ai;
    if (n < 6400) {
        int x = n % 80, y = n / 80;
        ai.hw = 6400; ai.off = n;
        ai.cx = (x + 0.5f) * 8.0f; ai.cy = (y + 0.5f) * 8.0f; ai.stride = 8.0f;
        ai.base = p0 + (size_t)b * CH * 6400;
    } else if (n < 8000) {
        int m = n - 6400; int x = m % 40, y = m / 40;
        ai.hw = 1600; ai.off = m;
        ai.cx = (x + 0.5f) * 16.0f; ai.cy = (y + 0.5f) * 16.0f; ai.stride = 16.0f;
        ai.base = p1 + (size_t)b * CH * 1600;
    } else {
        int m = n - 8000; int x = m % 20, y = m / 20;
        ai.hw = 400; ai.off = m;
        ai.cx = (x + 0.5f) * 32.0f; ai.cy = (y + 0.5f) * 32.0f; ai.stride = 32.0f;
        ai.base = p2 + (size_t)b * CH * 400;
    }
    return ai;
}

__device__ __forceinline__ void ins10(float a[10], float v) {
    if (v > a[9]) {
        a[9] = v;
#pragma unroll
        for (int i = 8; i >= 0; i--) {
            if (a[i + 1] > a[i]) { float t = a[i]; a[i] = a[i + 1]; a[i + 1] = t; }
        }
    }
}

__device__ __forceinline__ float iou_fn(float4 gb, float4 pb, float ap) {
    float ag = fmaxf(gb.z - gb.x, 0.f) * fmaxf(gb.w - gb.y, 0.f);
    float iw = fmaxf(fminf(gb.z, pb.z) - fmaxf(gb.x, pb.x), 0.f);
    float ih = fmaxf(fminf(gb.w, pb.w) - fmaxf(gb.y, pb.y), 0.f);
    float inter = iw * ih;
    return inter / (ag + ap - inter + 1e-7f);
}

// align metric — MUST be the same formula/op-order in k2, k3, k5 so the
// recomputed values are bit-identical to the ones that set the threshold.
__device__ __forceinline__ float align_metric(float s, float iou) {
    float sg = 1.f / (1.f + __expf(-s));
    float i2 = iou * iou;
    return sqrtf(sg) * i2 * i2 * i2;
}

__device__ __forceinline__ float ciou_fn(float4 p, float4 t) {
    float w1 = p.z - p.x, h1 = p.w - p.y;
    float w2 = t.z - t.x, h2 = t.w - t.y;
    float iw = fmaxf(fminf(p.z, t.z) - fmaxf(p.x, t.x), 0.f);
    float ih = fmaxf(fminf(p.w, t.w) - fmaxf(p.y, t.y), 0.f);
    float inter = iw * ih;
    float un = w1 * h1 + w2 * h2 - inter + 1e-7f;
    float iou = inter / un;
    float cw = fmaxf(p.z, t.z) - fminf(p.x, t.x);
    float chh = fmaxf(p.w, t.w) - fminf(p.y, t.y);
    float c2 = cw * cw + chh * chh + 1e-7f;
    float dx = p.x + p.z - t.x - t.z, dy = p.y + p.w - t.y - t.w;
    float rho2 = (dx * dx + dy * dy) * 0.25f;
    float da = atanf(w2 / (h2 + 1e-7f)) - atanf(w1 / (h1 + 1e-7f));
    float v = 0.4052847345693511f * da * da;
    float al = v / (v - iou + 1.f + 1e-7f);
    return iou - rho2 / c2 - al * v;
}

// ---------------- K1: fused decode (DFL softmax -> pred/lse) + BCE base, one pass ----------------
__global__ __launch_bounds__(256) void k1_fused(
    const float* __restrict__ p0, const float* __restrict__ p1, const float* __restrict__ p2,
    float* __restrict__ pred, float* __restrict__ lse, float* __restrict__ part_bce,
    float* __restrict__ posA, float* __restrict__ posI) {
    int blk = blockIdx.x;
    if (blk == 0) {  // absorb k0: zero pos maxima (k3 consumes them after this kernel completes)
        for (int i = threadIdx.x; i < NB * NG; i += 256) { posA[i] = 0.f; posI[i] = 0.f; }
    }
    int b = blk / TILES_PER_B;
    int tile = blk - b * TILES_PER_B;
    const float* base; int hw, o0, lvl_off, W; float spx;
    if (tile < 100)      { base = p0; hw = 6400; o0 = tile * 64;          lvl_off = 0;    W = 80; spx = 8.f;  }
    else if (tile < 125) { base = p1; hw = 1600; o0 = (tile - 100) * 64;  lvl_off = 6400; W = 40; spx = 16.f; }
    else                 { base = p2; hw = 400;  o0 = (tile - 125) * 64;  lvl_off = 8000; W = 20; spx = 32.f; }
    base += (size_t)b * CH * hw;
    int valid = min(64, hw - o0);

    // Phase A: DFL decode, thread = (local anchor, side)
    int a = threadIdx.x >> 2, k = threadIdx.x & 3;
    if (a < valid) {
        const float* col = base + (size_t)(k * 16) * hw + o0 + a;
        float v[16]; float mx = -1e30f;
#pragma unroll
        for (int j = 0; j < 16; j++) { v[j] = col[(size_t)j * hw]; mx = fmaxf(mx, v[j]); }
        float se = 0.f, we = 0.f;
#pragma unroll
        for (int j = 0; j < 16; j++) { float e = __expf(v[j] - mx); se += e; we += e * (float)j; }
        float dist = we / se * spx;
        float lv = mx + __logf(se);
        int nl = o0 + a;
        int x = nl % W, y = nl / W;
        float cx = (x + 0.5f) * spx, cy = (y + 0.5f) * spx;
        float c = (k & 1) ? cy : cx;
        size_t ai = (size_t)b * NTOT + lvl_off + nl;
        pred[ai * 4 + k] = (k < 2) ? (c - dist) : (c + dist);
        lse[ai * 4 + k] = lv;
    }

    // Phase B: BCE over the 80 cls channels of this tile (wave w covers channels w, w+4, ...)
    int wv = threadIdx.x >> 6, ln = threadIdx.x & 63;
    float bce = 0.f;
    if (ln < valid) {
        const float* cls = base + (size_t)64 * hw + o0 + ln;
        for (int c = wv; c < NC; c += 4) {
            float s = cls[(size_t)c * hw];
            bce += fmaxf(s, 0.f) + __logf(1.f + __expf(-fabsf(s)));
        }
    }
#pragma unroll
    for (int off = 32; off > 0; off >>= 1) bce += __shfl_xor(bce, off, 64);
    __shared__ float red[4];
    if ((threadIdx.x & 63) == 0) red[threadIdx.x >> 6] = bce;
    __syncthreads();
    if (threadIdx.x == 0)
        part_bce[blk] = red[0] + red[1] + red[2] + red[3];
}

// ---------------- K2: per (b,g) top-10 threshold (align computed on the fly, not stored) ----------------
__global__ __launch_bounds__(256) void k2_thr(
    const float* __restrict__ p0, const float* __restrict__ p1, const float* __restrict__ p2,
    const float* __restrict__ gtb, const int* __restrict__ gtl,
    const float* __restrict__ pred, float* __restrict__ thr) {
    int g = blockIdx.x, b = blockIdx.y;
    const float* gb = gtb + (size_t)(b * NG + g) * 4;
    float gx1 = gb[0], gy1 = gb[1], gx2 = gb[2], gy2 = gb[3];
    bool vg = (gx1 + gy1 + gx2 + gy2) > 0.f;
    int label = gtl[b * NG + g];
    float4 gb4 = { gx1, gy1, gx2, gy2 };
    float top[10];
#pragma unroll
    for (int i = 0; i < 10; i++) top[i] = -1.f;
    for (int n = threadIdx.x; n < NTOT; n += 256) {
        AInfo ai = anchor_info(n, b, p0, p1, p2);
        float4 pb = ((const float4*)pred)[(size_t)b * NTOT + n];
        float ap = fmaxf(pb.z - pb.x, 0.f) * fmaxf(pb.w - pb.y, 0.f);
        float iou = iou_fn(gb4, pb, ap);
        bool ing = (ai.cx > gx1) && (ai.cx < gx2) && (ai.cy > gy1) && (ai.cy < gy2);
        float al = 0.f;
        if (ing && vg) {
            float s = ai.base[(size_t)(64 + label) * ai.hw + ai.off];
            al = align_metric(s, iou);
        }
        ins10(top, al);
    }
    __shared__ float s_top[256 * 10];
#pragma unroll
    for (int i = 0; i < 10; i++) s_top[threadIdx.x * 10 + i] = top[i];
    __syncthreads();
    if (threadIdx.x < 64) {
        float mt[10];
#pragma unroll
        for (int i = 0; i < 10; i++) mt[i] = -1.f;
        for (int src = threadIdx.x; src < 256; src += 64)
#pragma unroll
            for (int i = 0; i < 10; i++) ins10(mt, s_top[src * 10 + i]);
        float thrv = 0.f;
        for (int r = 0; r < 10; r++) {
            unsigned long long key = ((unsigned long long)__float_as_uint(mt[0]) << 32) | (unsigned)threadIdx.x;
#pragma unroll
            for (int off = 32; off > 0; off >>= 1) {
                unsigned long long o = __shfl_xor(key, off, 64);
                if (o > key) key = o;
            }
            thrv = __uint_as_float((unsigned)(key >> 32));
            if ((key & 63ULL) == (unsigned long long)threadIdx.x) {
#pragma unroll
                for (int i = 0; i < 9; i++) mt[i] = mt[i + 1];
                mt[9] = -1.f;
            }
        }
        if (threadIdx.x == 0) thr[b * NG + g] = thrv;
    }
}

// ---------------- K3: per (b,n) mask (align recomputed), matched, pos maxima, num_pos partial ----------------
__global__ __launch_bounds__(256) void k3_mask(
    const float* __restrict__ p0, const float* __restrict__ p1, const float* __restrict__ p2,
    const float* __restrict__ thr, const float* __restrict__ pred,
    const float* __restrict__ gtb, const int* __restrict__ gtl,
    unsigned* __restrict__ maskv, int* __restrict__ matchedv,
    float* __restrict__ posA, float* __restrict__ posI, unsigned* __restrict__ partN) {
    int b = blockIdx.y;
    int n = blockIdx.x * 256 + threadIdx.x;
    __shared__ float s_thr[NG];
    __shared__ float4 s_gt[NG];
    __shared__ int s_lab[NG];
    if (threadIdx.x < NG) {
        s_thr[threadIdx.x] = thr[b * NG + threadIdx.x];
        s_gt[threadIdx.x] = ((const float4*)gtb)[b * NG + threadIdx.x];
        s_lab[threadIdx.x] = gtl[b * NG + threadIdx.x];
    }
    __syncthreads();
    bool fg = false;
    if (n < NTOT) {
        AInfo ai = anchor_info(n, b, p0, p1, p2);
        float4 pb = ((const float4*)pred)[(size_t)b * NTOT + n];
        float ap = fmaxf(pb.z - pb.x, 0.f) * fmaxf(pb.w - pb.y, 0.f);
        unsigned m = 0;
#pragma unroll 4
        for (int g = 0; g < NG; g++) {
            float4 gb4 = s_gt[g];
            bool vg = (gb4.x + gb4.y + gb4.z + gb4.w) > 0.f;
            float iou = iou_fn(gb4, pb, ap);
            bool ing = (ai.cx > gb4.x) && (ai.cx < gb4.z) && (ai.cy > gb4.y) && (ai.cy < gb4.w);
            float al = 0.f;
            if (ing && vg) {
                float s = ai.base[(size_t)(64 + s_lab[g]) * ai.hw + ai.off];
                al = align_metric(s, iou);
            }
            if (al >= s_thr[g] && al > 1e-9f) m |= (1u << g);
        }
        int cnt = __popc(m);
        int matched = -1;
        if (cnt > 0) {
            if (cnt > 1) {
                float best = -1.f; int bg = 0;
                for (int g = 0; g < NG; g++) {
                    float iou = iou_fn(s_gt[g], pb, ap);
                    if (iou > best) { best = iou; bg = g; }
                }
                m = 1u << bg;  // best_oh replaces mask when multi
            }
            for (int g = 0; g < NG; g++) {
                if ((m >> g) & 1u) {
                    float4 gb4 = s_gt[g];
                    bool vg = (gb4.x + gb4.y + gb4.z + gb4.w) > 0.f;
                    float iou = iou_fn(gb4, pb, ap);
                    bool ing = (ai.cx > gb4.x) && (ai.cx < gb4.z) && (ai.cy > gb4.y) && (ai.cy < gb4.w);
                    float al = 0.f;
                    if (ing && vg) {
                        float s = ai.base[(size_t)(64 + s_lab[g]) * ai.hw + ai.off];
                        al = align_metric(s, iou);
                    }
                    atomicMax((int*)&posI[b * NG + g], __float_as_int(iou));
                    atomicMax((int*)&posA[b * NG + g], __float_as_int(al));
                }
            }
            matched = __ffs(m) - 1;
            fg = true;
        }
        maskv[(size_t)b * NTOT + n] = m;
        matchedv[(size_t)b * NTOT + n] = matched;
    }
    unsigned long long bal = __ballot(fg);
    __shared__ unsigned redN[4];
    if ((threadIdx.x & 63) == 0) redN[threadIdx.x >> 6] = (unsigned)__popcll(bal);
    __syncthreads();
    if (threadIdx.x == 0)
        partN[blockIdx.y * gridDim.x + blockIdx.x] = redN[0] + redN[1] + redN[2] + redN[3];
}

// ---------------- K5: fg losses (norm via recomputed align, bce-corr, ciou, dfl) ----------------
__global__ __launch_bounds__(256) void k5_loss(
    const float* __restrict__ p0, const float* __restrict__ p1, const float* __restrict__ p2,
    const unsigned* __restrict__ maskv, const int* __restrict__ matchedv,
    const float* __restrict__ posA, const float* __restrict__ posI,
    const float* __restrict__ gtb, const int* __restrict__ gtl,
    const float* __restrict__ pred, const float* __restrict__ lse,
    float* __restrict__ part_corr, float* __restrict__ part_liou, float* __restrict__ part_ldfl) {
    int b = blockIdx.y;
    int n = blockIdx.x * 256 + threadIdx.x;
    __shared__ float4 s_gt[NG];
    __shared__ int s_lab[NG];
    __shared__ float s_pa[NG], s_pi[NG];
    if (threadIdx.x < NG) {
        s_gt[threadIdx.x] = ((const float4*)gtb)[b * NG + threadIdx.x];
        s_lab[threadIdx.x] = gtl[b * NG + threadIdx.x];
        s_pa[threadIdx.x] = posA[b * NG + threadIdx.x];
        s_pi[threadIdx.x] = posI[b * NG + threadIdx.x];
    }
    __syncthreads();
    float corr = 0.f, liou = 0.f, ldfl = 0.f;
    if (n < NTOT) {
        int mt = matchedv[(size_t)b * NTOT + n];
        if (mt >= 0) {
            AInfo ai = anchor_info(n, b, p0, p1, p2);
            const float* base = ai.base + ai.off;
            float4 pb = ((const float4*)pred)[(size_t)b * NTOT + n];
            float ap = fmaxf(pb.z - pb.x, 0.f) * fmaxf(pb.w - pb.y, 0.f);
            unsigned m = maskv[(size_t)b * NTOT + n];
            float nrm = 0.f;
            for (int g = 0; g < NG; g++) {
                if ((m >> g) & 1u) {
                    float4 gb4 = s_gt[g];
                    bool vg = (gb4.x + gb4.y + gb4.z + gb4.w) > 0.f;
                    float iou = iou_fn(gb4, pb, ap);
                    bool ing = (ai.cx > gb4.x) && (ai.cx < gb4.z) && (ai.cy > gb4.y) && (ai.cy < gb4.w);
                    float al = 0.f;
                    if (ing && vg) {
                        float s = base[(size_t)(64 + s_lab[g]) * ai.hw];
                        al = align_metric(s, iou);
                    }
                    nrm = fmaxf(nrm, al * s_pi[g] / (s_pa[g] + 1e-9f));
                }
            }
            float s = base[(size_t)(64 + s_lab[mt]) * ai.hw];
            corr = s * nrm;
            float4 tb = s_gt[mt];
            liou = 1.f - ciou_fn(pb, tb);
            float4 l4 = ((const float4*)lse)[(size_t)b * NTOT + n];
            float lv[4] = { l4.x, l4.y, l4.z, l4.w };
            float d[4] = { fmaxf(ai.cx - tb.x, 0.f), fmaxf(ai.cy - tb.y, 0.f),
                           fmaxf(tb.z - ai.cx, 0.f), fmaxf(tb.w - ai.cy, 0.f) };
#pragma unroll
            for (int k = 0; k < 4; k++) {
                float tbk = fminf(d[k], 14.999999f);
                float lo = floorf(tbk);
                float afr = tbk - lo;
                int li = (int)lo;
                int ui = min(li + 1, 15);
                float Ll = base[(size_t)(k * 16 + li) * ai.hw];
                float Lu = base[(size_t)(k * 16 + ui) * ai.hw];
                ldfl += lv[k] - ((1.f - afr) * Ll + afr * Lu);
            }
        }
    }
#pragma unroll
    for (int off = 32; off > 0; off >>= 1) {
        corr += __shfl_xor(corr, off, 64);
        liou += __shfl_xor(liou, off, 64);
        ldfl += __shfl_xor(ldfl, off, 64);
    }
    __shared__ float rc[4], ri[4], rd[4];
    if ((threadIdx.x & 63) == 0) {
        int w = threadIdx.x >> 6;
        rc[w] = corr; ri[w] = liou; rd[w] = ldfl;
    }
    __syncthreads();
    if (threadIdx.x == 0) {
        int blk = blockIdx.y * gridDim.x + blockIdx.x;
        part_corr[blk] = rc[0] + rc[1] + rc[2] + rc[3];
        part_liou[blk] = ri[0] + ri[1] + ri[2] + ri[3];
        part_ldfl[blk] = rd[0] + rd[1] + rd[2] + rd[3];
    }
}

// ---------------- K6: final reduce in fp64 ----------------
__global__ __launch_bounds__(256) void k6_final(
    const float* __restrict__ part_bce, const float* __restrict__ part_corr,
    const float* __restrict__ part_liou, const float* __restrict__ part_ldfl,
    const unsigned* __restrict__ partN, float* __restrict__ out) {
    double bce = 0.0, corr = 0.0, liou = 0.0, ldfl = 0.0, np = 0.0;
    for (int i = threadIdx.x; i < NBLK1; i += 256) bce += (double)part_bce[i];
    for (int i = threadIdx.x; i < NBLK3; i += 256) {
        corr += (double)part_corr[i];
        liou += (double)part_liou[i];
        ldfl += (double)part_ldfl[i];
        np   += (double)partN[i];
    }
#pragma unroll
    for (int off = 32; off > 0; off >>= 1) {
        bce  += __shfl_xor(bce, off, 64);
        corr += __shfl_xor(corr, off, 64);
        liou += __shfl_xor(liou, off, 64);
        ldfl += __shfl_xor(ldfl, off, 64);
        np   += __shfl_xor(np, off, 64);
    }
    __shared__ double rb[4], rc[4], ri[4], rd[4], rn[4];
    if ((threadIdx.x & 63) == 0) {
        int w = threadIdx.x >> 6;
        rb[w] = bce; rc[w] = corr; ri[w] = liou; rd[w] = ldfl; rn[w] = np;
    }
    __syncthreads();
    if (threadIdx.x == 0) {
        bce  = rb[0] + rb[1] + rb[2] + rb[3];
        corr = rc[0] + rc[1] + rc[2] + rc[3];
        liou = ri[0] + ri[1] + ri[2] + ri[3];
        ldfl = rd[0] + rd[1] + rd[2] + rd[3];
        np   = rn[0] + rn[1] + rn[2] + rn[3];
        if (np < 1.0) np = 1.0;
        out[0] = (float)(7.5 * liou / np);            // W_IOU * loss_iou
        out[1] = (float)(0.5 * (bce - corr) / np);    // W_CLS * loss_cls
        out[2] = (float)(1.5 * ldfl / np);            // W_DFL * loss_dfl
    }
}

extern "C" void kernel_launch(void* const* d_in, const int* in_sizes, int n_in,
                              void* d_out, int out_size, void* d_ws, size_t ws_size,
                              hipStream_t stream) {
    const float* p0 = (const float*)d_in[0];
    const float* p1 = (const float*)d_in[1];
    const float* p2 = (const float*)d_in[2];
    const float* gtb = (const float*)d_in[3];
    const int* gtl = (const int*)d_in[4];
    float* out = (float*)d_out;

    char* w = (char*)d_ws;
    float* pred = (float*)w;                          // BN*4 floats (4.3 MB)
    float* lse = pred + (size_t)BN * 4;               // BN*4 floats (4.3 MB)
    float* thr = lse + (size_t)BN * 4;                // 1024
    float* posA = thr + NB * NG;                      // 1024
    float* posI = posA + NB * NG;                     // 1024
    unsigned* maskv = (unsigned*)(posI + NB * NG);    // BN (1.07 MB)
    int* matchedv = (int*)(maskv + BN);               // BN (1.07 MB)
    float* part_bce = (float*)(matchedv + BN);        // 4224 floats
    float* part_corr = part_bce + NBLK1;              // 1056
    float* part_liou = part_corr + NBLK3;             // 1056
    float* part_ldfl = part_liou + NBLK3;             // 1056
    unsigned* partN = (unsigned*)(part_ldfl + NBLK3); // 1056

    hipLaunchKernelGGL(k1_fused, dim3(NBLK1), dim3(256), 0, stream,
                       p0, p1, p2, pred, lse, part_bce, posA, posI);
    hipLaunchKernelGGL(k2_thr, dim3(NG, NB), dim3(256), 0, stream,
                       p0, p1, p2, gtb, gtl, pred, thr);
    hipLaunchKernelGGL(k3_mask, dim3(NBLKN, NB), dim3(256), 0, stream,
                       p0, p1, p2, thr, pred, gtb, gtl, maskv, matchedv, posA, posI, partN);
    hipLaunchKernelGGL(k5_loss, dim3(NBLKN, NB), dim3(256), 0, stream,
                       p0, p1, p2, maskv, matchedv, posA, posI, gtb, gtl, pred, lse,
                       part_corr, part_liou, part_ldfl);
    hipLaunchKernelGGL(k6_final, dim3(1), dim3(256), 0, stream,
                       part_bce, part_corr, part_liou, part_ldfl, partN, out);
}

// Round 6
// 267.482 us; speedup vs baseline: 1.0334x; 1.0334x over previous
//
#include <hip/hip_runtime.h>
#include <hip/hip_bf16.h>

// Problem constants
#define NB 32          // batch
#define NG 32          // max gts
#define NC 80          // classes
#define NTOT 8400      // 6400 + 1600 + 400
#define CH 144
#define BN (NB * NTOT)            // 268800 anchors total

#define TILES_PER_B 132           // 100 (l0) + 25 (l1) + 7 (l2, last partial)
#define NBLK1 (NB * TILES_PER_B)  // 4224
#define NBLKN 33                  // ceil(NTOT/256)
#define NBLK3 (NBLKN * NB)        // 1056

struct AInfo {
    const float* base;  // p[lvl] + b*144*hw  (channel-major)
    int hw;
    int off;
    float cx, cy, stride;
};

__device__ __forceinline__ AInfo anchor_info(int n, int b, const float* p0, const float* p1, const float* p2) {
    AInfo ai;
    if (n < 6400) {
        int x = n % 80, y = n / 80;
        ai.hw = 6400; ai.off = n;
        ai.cx = (x + 0.5f) * 8.0f; ai.cy = (y + 0.5f) * 8.0f; ai.stride = 8.0f;
        ai.base = p0 + (size_t)b * CH * 6400;
    } else if (n < 8000) {
        int m = n - 6400; int x = m % 40, y = m / 40;
        ai.hw = 1600; ai.off = m;
        ai.cx = (x + 0.5f) * 16.0f; ai.cy = (y + 0.5f) * 16.0f; ai.stride = 16.0f;
        ai.base = p1 + (size_t)b * CH * 1600;
    } else {
        int m = n - 8000; int x = m % 20, y = m / 20;
        ai.hw = 400; ai.off = m;
        ai.cx = (x + 0.5f) * 32.0f; ai.cy = (y + 0.5f) * 32.0f; ai.stride = 32.0f;
        ai.base = p2 + (size_t)b * CH * 400;
    }
    return ai;
}

__device__ __forceinline__ void ins10(float a[10], float v) {
    if (v > a[9]) {
        a[9] = v;
#pragma unroll
        for (int i = 8; i >= 0; i--) {
            if (a[i + 1] > a[i]) { float t = a[i]; a[i] = a[i + 1]; a[i + 1] = t; }
        }
    }
}

__device__ __forceinline__ float iou_fn(float4 gb, float4 pb, float ap) {
    float ag = fmaxf(gb.z - gb.x, 0.f) * fmaxf(gb.w - gb.y, 0.f);
    float iw = fmaxf(fminf(gb.z, pb.z) - fmaxf(gb.x, pb.x), 0.f);
    float ih = fmaxf(fminf(gb.w, pb.w) - fmaxf(gb.y, pb.y), 0.f);
    float inter = iw * ih;
    return inter / (ag + ap - inter + 1e-7f);
}

// align metric — same formula/op-order in k2, k3, k5 so recomputed values are bit-identical.
__device__ __forceinline__ float align_metric(float s, float iou) {
    float sg = 1.f / (1.f + __expf(-s));
    float i2 = iou * iou;
    return sqrtf(sg) * i2 * i2 * i2;
}

__device__ __forceinline__ float ciou_fn(float4 p, float4 t) {
    float w1 = p.z - p.x, h1 = p.w - p.y;
    float w2 = t.z - t.x, h2 = t.w - t.y;
    float iw = fmaxf(fminf(p.z, t.z) - fmaxf(p.x, t.x), 0.f);
    float ih = fmaxf(fminf(p.w, t.w) - fmaxf(p.y, t.y), 0.f);
    float inter = iw * ih;
    float un = w1 * h1 + w2 * h2 - inter + 1e-7f;
    float iou = inter / un;
    float cw = fmaxf(p.z, t.z) - fminf(p.x, t.x);
    float chh = fmaxf(p.w, t.w) - fminf(p.y, t.y);
    float c2 = cw * cw + chh * chh + 1e-7f;
    float dx = p.x + p.z - t.x - t.z, dy = p.y + p.w - t.y - t.w;
    float rho2 = (dx * dx + dy * dy) * 0.25f;
    float da = atanf(w2 / (h2 + 1e-7f)) - atanf(w1 / (h1 + 1e-7f));
    float v = 0.4052847345693511f * da * da;
    float al = v / (v - iou + 1.f + 1e-7f);
    return iou - rho2 / c2 - al * v;
}

// ---------------- K1: fused decode (DFL softmax -> pred/lse) + BCE base, one pass ----------------
__global__ __launch_bounds__(256) void k1_fused(
    const float* __restrict__ p0, const float* __restrict__ p1, const float* __restrict__ p2,
    float* __restrict__ pred, float* __restrict__ lse, float* __restrict__ part_bce,
    float* __restrict__ posA, float* __restrict__ posI) {
    int blk = blockIdx.x;
    if (blk == 0) {  // absorb k0: zero pos maxima (k3 consumes them after this kernel completes)
        for (int i = threadIdx.x; i < NB * NG; i += 256) { posA[i] = 0.f; posI[i] = 0.f; }
    }
    int b = blk / TILES_PER_B;
    int tile = blk - b * TILES_PER_B;
    const float* base; int hw, o0, lvl_off, W; float spx;
    if (tile < 100)      { base = p0; hw = 6400; o0 = tile * 64;          lvl_off = 0;    W = 80; spx = 8.f;  }
    else if (tile < 125) { base = p1; hw = 1600; o0 = (tile - 100) * 64;  lvl_off = 6400; W = 40; spx = 16.f; }
    else                 { base = p2; hw = 400;  o0 = (tile - 125) * 64;  lvl_off = 8000; W = 20; spx = 32.f; }
    base += (size_t)b * CH * hw;
    int valid = min(64, hw - o0);

    // Phase A: DFL decode, thread = (local anchor, side); 16 independent loads batched
    int a = threadIdx.x >> 2, k = threadIdx.x & 3;
    if (a < valid) {
        const float* col = base + (size_t)(k * 16) * hw + o0 + a;
        float v[16]; float mx = -1e30f;
#pragma unroll
        for (int j = 0; j < 16; j++) v[j] = col[(size_t)j * hw];
#pragma unroll
        for (int j = 0; j < 16; j++) mx = fmaxf(mx, v[j]);
        float se = 0.f, we = 0.f;
#pragma unroll
        for (int j = 0; j < 16; j++) { float e = __expf(v[j] - mx); se += e; we += e * (float)j; }
        float dist = we / se * spx;
        float lv = mx + __logf(se);
        int nl = o0 + a;
        int x = nl % W, y = nl / W;
        float cx = (x + 0.5f) * spx, cy = (y + 0.5f) * spx;
        float c = (k & 1) ? cy : cx;
        size_t ai = (size_t)b * NTOT + lvl_off + nl;
        pred[ai * 4 + k] = (k < 2) ? (c - dist) : (c + dist);
        lse[ai * 4 + k] = lv;
    }

    // Phase B: BCE over 80 cls channels (wave wv covers channels wv, wv+4, ... — 20 each),
    // all 20 loads issued as an independent batch (breaks the load->use serialization).
    int wv = threadIdx.x >> 6, ln = threadIdx.x & 63;
    float bce = 0.f;
    if (ln < valid) {
        const float* cls = base + (size_t)64 * hw + o0 + ln;
        float vv[20];
#pragma unroll
        for (int it = 0; it < 20; it++) vv[it] = cls[(size_t)(wv + it * 4) * hw];
#pragma unroll
        for (int it = 0; it < 20; it++) {
            float s = vv[it];
            bce += fmaxf(s, 0.f) + __logf(1.f + __expf(-fabsf(s)));
        }
    }
#pragma unroll
    for (int off = 32; off > 0; off >>= 1) bce += __shfl_xor(bce, off, 64);
    __shared__ float red[4];
    if ((threadIdx.x & 63) == 0) red[threadIdx.x >> 6] = bce;
    __syncthreads();
    if (threadIdx.x == 0)
        part_bce[blk] = red[0] + red[1] + red[2] + red[3];
}

// ---------------- K2: per (b,g) top-10 threshold (align on the fly; 4 anchors/thread/iter) ----------------
__global__ __launch_bounds__(256) void k2_thr(
    const float* __restrict__ p0, const float* __restrict__ p1, const float* __restrict__ p2,
    const float* __restrict__ gtb, const int* __restrict__ gtl,
    const float* __restrict__ pred, float* __restrict__ thr) {
    int g = blockIdx.x, b = blockIdx.y;
    const float* gb = gtb + (size_t)(b * NG + g) * 4;
    float gx1 = gb[0], gy1 = gb[1], gx2 = gb[2], gy2 = gb[3];
    bool vg = (gx1 + gy1 + gx2 + gy2) > 0.f;
    int label = gtl[b * NG + g];
    float4 gb4 = { gx1, gy1, gx2, gy2 };
    float top[10];
#pragma unroll
    for (int i = 0; i < 10; i++) top[i] = -1.f;
    const float4* pred4 = (const float4*)pred + (size_t)b * NTOT;
    for (int it = 0; it < 9; it++) {   // ceil(8400/1024)
        int n0 = it * 1024 + threadIdx.x;
        float4 pb[4]; float sc[4]; AInfo aii[4]; bool ok[4];
#pragma unroll
        for (int j = 0; j < 4; j++) {
            int n = n0 + j * 256;
            ok[j] = (n < NTOT);
            if (ok[j]) {
                aii[j] = anchor_info(n, b, p0, p1, p2);
                pb[j] = pred4[n];
                sc[j] = aii[j].base[(size_t)(64 + label) * aii[j].hw + aii[j].off];
            }
        }
#pragma unroll
        for (int j = 0; j < 4; j++) {
            if (!ok[j]) continue;
            float ap = fmaxf(pb[j].z - pb[j].x, 0.f) * fmaxf(pb[j].w - pb[j].y, 0.f);
            float iou = iou_fn(gb4, pb[j], ap);
            bool ing = (aii[j].cx > gx1) && (aii[j].cx < gx2) && (aii[j].cy > gy1) && (aii[j].cy < gy2);
            float al = 0.f;
            if (ing && vg) al = align_metric(sc[j], iou);
            ins10(top, al);
        }
    }
    __shared__ float s_top[256 * 10];
#pragma unroll
    for (int i = 0; i < 10; i++) s_top[threadIdx.x * 10 + i] = top[i];
    __syncthreads();
    if (threadIdx.x < 64) {
        float mt[10];
#pragma unroll
        for (int i = 0; i < 10; i++) mt[i] = -1.f;
        for (int src = threadIdx.x; src < 256; src += 64)
#pragma unroll
            for (int i = 0; i < 10; i++) ins10(mt, s_top[src * 10 + i]);
        float thrv = 0.f;
        for (int r = 0; r < 10; r++) {
            unsigned long long key = ((unsigned long long)__float_as_uint(mt[0]) << 32) | (unsigned)threadIdx.x;
#pragma unroll
            for (int off = 32; off > 0; off >>= 1) {
                unsigned long long o = __shfl_xor(key, off, 64);
                if (o > key) key = o;
            }
            thrv = __uint_as_float((unsigned)(key >> 32));
            if ((key & 63ULL) == (unsigned long long)threadIdx.x) {
#pragma unroll
                for (int i = 0; i < 9; i++) mt[i] = mt[i + 1];
                mt[9] = -1.f;
            }
        }
        if (threadIdx.x == 0) thr[b * NG + g] = thrv;
    }
}

// ---------------- K3: per (b,n) mask (align recomputed), matched, pos maxima, num_pos partial ----------------
__global__ __launch_bounds__(256) void k3_mask(
    const float* __restrict__ p0, const float* __restrict__ p1, const float* __restrict__ p2,
    const float* __restrict__ thr, const float* __restrict__ pred,
    const float* __restrict__ gtb, const int* __restrict__ gtl,
    unsigned* __restrict__ maskv, int* __restrict__ matchedv,
    float* __restrict__ posA, float* __restrict__ posI, unsigned* __restrict__ partN) {
    int b = blockIdx.y;
    int n = blockIdx.x * 256 + threadIdx.x;
    __shared__ float s_thr[NG];
    __shared__ float4 s_gt[NG];
    __shared__ int s_lab[NG];
    if (threadIdx.x < NG) {
        s_thr[threadIdx.x] = thr[b * NG + threadIdx.x];
        s_gt[threadIdx.x] = ((const float4*)gtb)[b * NG + threadIdx.x];
        s_lab[threadIdx.x] = gtl[b * NG + threadIdx.x];
    }
    __syncthreads();
    bool fg = false;
    if (n < NTOT) {
        AInfo ai = anchor_info(n, b, p0, p1, p2);
        float4 pb = ((const float4*)pred)[(size_t)b * NTOT + n];
        float ap = fmaxf(pb.z - pb.x, 0.f) * fmaxf(pb.w - pb.y, 0.f);
        unsigned m = 0;
#pragma unroll 8
        for (int g = 0; g < NG; g++) {
            float4 gb4 = s_gt[g];
            bool vg = (gb4.x + gb4.y + gb4.z + gb4.w) > 0.f;
            float iou = iou_fn(gb4, pb, ap);
            bool ing = (ai.cx > gb4.x) && (ai.cx < gb4.z) && (ai.cy > gb4.y) && (ai.cy < gb4.w);
            float al = 0.f;
            if (ing && vg) {
                float s = ai.base[(size_t)(64 + s_lab[g]) * ai.hw + ai.off];
                al = align_metric(s, iou);
            }
            if (al >= s_thr[g] && al > 1e-9f) m |= (1u << g);
        }
        int cnt = __popc(m);
        int matched = -1;
        if (cnt > 0) {
            if (cnt > 1) {
                float best = -1.f; int bg = 0;
                for (int g = 0; g < NG; g++) {
                    float iou = iou_fn(s_gt[g], pb, ap);
                    if (iou > best) { best = iou; bg = g; }
                }
                m = 1u << bg;  // best_oh replaces mask when multi
            }
            for (int g = 0; g < NG; g++) {
                if ((m >> g) & 1u) {
                    float4 gb4 = s_gt[g];
                    bool vg = (gb4.x + gb4.y + gb4.z + gb4.w) > 0.f;
                    float iou = iou_fn(gb4, pb, ap);
                    bool ing = (ai.cx > gb4.x) && (ai.cx < gb4.z) && (ai.cy > gb4.y) && (ai.cy < gb4.w);
                    float al = 0.f;
                    if (ing && vg) {
                        float s = ai.base[(size_t)(64 + s_lab[g]) * ai.hw + ai.off];
                        al = align_metric(s, iou);
                    }
                    atomicMax((int*)&posI[b * NG + g], __float_as_int(iou));
                    atomicMax((int*)&posA[b * NG + g], __float_as_int(al));
                }
            }
            matched = __ffs(m) - 1;
            fg = true;
        }
        maskv[(size_t)b * NTOT + n] = m;
        matchedv[(size_t)b * NTOT + n] = matched;
    }
    unsigned long long bal = __ballot(fg);
    __shared__ unsigned redN[4];
    if ((threadIdx.x & 63) == 0) redN[threadIdx.x >> 6] = (unsigned)__popcll(bal);
    __syncthreads();
    if (threadIdx.x == 0)
        partN[blockIdx.y * gridDim.x + blockIdx.x] = redN[0] + redN[1] + redN[2] + redN[3];
}

// ---------------- K5: fg losses (norm via recomputed align, bce-corr, ciou, dfl) ----------------
__global__ __launch_bounds__(256) void k5_loss(
    const float* __restrict__ p0, const float* __restrict__ p1, const float* __restrict__ p2,
    const unsigned* __restrict__ maskv, const int* __restrict__ matchedv,
    const float* __restrict__ posA, const float* __restrict__ posI,
    const float* __restrict__ gtb, const int* __restrict__ gtl,
    const float* __restrict__ pred, const float* __restrict__ lse,
    float* __restrict__ part_corr, float* __restrict__ part_liou, float* __restrict__ part_ldfl) {
    int b = blockIdx.y;
    int n = blockIdx.x * 256 + threadIdx.x;
    __shared__ float4 s_gt[NG];
    __shared__ int s_lab[NG];
    __shared__ float s_pa[NG], s_pi[NG];
    if (threadIdx.x < NG) {
        s_gt[threadIdx.x] = ((const float4*)gtb)[b * NG + threadIdx.x];
        s_lab[threadIdx.x] = gtl[b * NG + threadIdx.x];
        s_pa[threadIdx.x] = posA[b * NG + threadIdx.x];
        s_pi[threadIdx.x] = posI[b * NG + threadIdx.x];
    }
    __syncthreads();
    float corr = 0.f, liou = 0.f, ldfl = 0.f;
    if (n < NTOT) {
        int mt = matchedv[(size_t)b * NTOT + n];
        if (mt >= 0) {
            AInfo ai = anchor_info(n, b, p0, p1, p2);
            const float* base = ai.base + ai.off;
            float4 pb = ((const float4*)pred)[(size_t)b * NTOT + n];
            float ap = fmaxf(pb.z - pb.x, 0.f) * fmaxf(pb.w - pb.y, 0.f);
            unsigned m = maskv[(size_t)b * NTOT + n];
            float nrm = 0.f;
#pragma unroll 4
            for (int g = 0; g < NG; g++) {
                if ((m >> g) & 1u) {
                    float4 gb4 = s_gt[g];
                    bool vg = (gb4.x + gb4.y + gb4.z + gb4.w) > 0.f;
                    float iou = iou_fn(gb4, pb, ap);
                    bool ing = (ai.cx > gb4.x) && (ai.cx < gb4.z) && (ai.cy > gb4.y) && (ai.cy < gb4.w);
                    float al = 0.f;
                    if (ing && vg) {
                        float s = base[(size_t)(64 + s_lab[g]) * ai.hw];
                        al = align_metric(s, iou);
                    }
                    nrm = fmaxf(nrm, al * s_pi[g] / (s_pa[g] + 1e-9f));
                }
            }
            float s = base[(size_t)(64 + s_lab[mt]) * ai.hw];
            corr = s * nrm;
            float4 tb = s_gt[mt];
            liou = 1.f - ciou_fn(pb, tb);
            float4 l4 = ((const float4*)lse)[(size_t)b * NTOT + n];
            float lv[4] = { l4.x, l4.y, l4.z, l4.w };
            float d[4] = { fmaxf(ai.cx - tb.x, 0.f), fmaxf(ai.cy - tb.y, 0.f),
                           fmaxf(tb.z - ai.cx, 0.f), fmaxf(tb.w - ai.cy, 0.f) };
            float Ls[8];
            int li4[4], ui4[4]; float afr4[4];
#pragma unroll
            for (int k = 0; k < 4; k++) {
                float tbk = fminf(d[k], 14.999999f);
                float lo = floorf(tbk);
                afr4[k] = tbk - lo;
                li4[k] = (int)lo;
                ui4[k] = min(li4[k] + 1, 15);
            }
#pragma unroll
            for (int k = 0; k < 4; k++) {
                Ls[k * 2]     = base[(size_t)(k * 16 + li4[k]) * ai.hw];
                Ls[k * 2 + 1] = base[(size_t)(k * 16 + ui4[k]) * ai.hw];
            }
#pragma unroll
            for (int k = 0; k < 4; k++)
                ldfl += lv[k] - ((1.f - afr4[k]) * Ls[k * 2] + afr4[k] * Ls[k * 2 + 1]);
        }
    }
#pragma unroll
    for (int off = 32; off > 0; off >>= 1) {
        corr += __shfl_xor(corr, off, 64);
        liou += __shfl_xor(liou, off, 64);
        ldfl += __shfl_xor(ldfl, off, 64);
    }
    __shared__ float rc[4], ri[4], rd[4];
    if ((threadIdx.x & 63) == 0) {
        int w = threadIdx.x >> 6;
        rc[w] = corr; ri[w] = liou; rd[w] = ldfl;
    }
    __syncthreads();
    if (threadIdx.x == 0) {
        int blk = blockIdx.y * gridDim.x + blockIdx.x;
        part_corr[blk] = rc[0] + rc[1] + rc[2] + rc[3];
        part_liou[blk] = ri[0] + ri[1] + ri[2] + ri[3];
        part_ldfl[blk] = rd[0] + rd[1] + rd[2] + rd[3];
    }
}

// ---------------- K6: final reduce in fp64 ----------------
__global__ __launch_bounds__(256) void k6_final(
    const float* __restrict__ part_bce, const float* __restrict__ part_corr,
    const float* __restrict__ part_liou, const float* __restrict__ part_ldfl,
    const unsigned* __restrict__ partN, float* __restrict__ out) {
    double bce = 0.0, corr = 0.0, liou = 0.0, ldfl = 0.0, np = 0.0;
    for (int i = threadIdx.x; i < NBLK1; i += 256) bce += (double)part_bce[i];
    for (int i = threadIdx.x; i < NBLK3; i += 256) {
        corr += (double)part_corr[i];
        liou += (double)part_liou[i];
        ldfl += (double)part_ldfl[i];
        np   += (double)partN[i];
    }
#pragma unroll
    for (int off = 32; off > 0; off >>= 1) {
        bce  += __shfl_xor(bce, off, 64);
        corr += __shfl_xor(corr, off, 64);
        liou += __shfl_xor(liou, off, 64);
        ldfl += __shfl_xor(ldfl, off, 64);
        np   += __shfl_xor(np, off, 64);
    }
    __shared__ double rb[4], rc[4], ri[4], rd[4], rn[4];
    if ((threadIdx.x & 63) == 0) {
        int w = threadIdx.x >> 6;
        rb[w] = bce; rc[w] = corr; ri[w] = liou; rd[w] = ldfl; rn[w] = np;
    }
    __syncthreads();
    if (threadIdx.x == 0) {
        bce  = rb[0] + rb[1] + rb[2] + rb[3];
        corr = rc[0] + rc[1] + rc[2] + rc[3];
        liou = ri[0] + ri[1] + ri[2] + ri[3];
        ldfl = rd[0] + rd[1] + rd[2] + rd[3];
        np   = rn[0] + rn[1] + rn[2] + rn[3];
        if (np < 1.0) np = 1.0;
        out[0] = (float)(7.5 * liou / np);            // W_IOU * loss_iou
        out[1] = (float)(0.5 * (bce - corr) / np);    // W_CLS * loss_cls
        out[2] = (float)(1.5 * ldfl / np);            // W_DFL * loss_dfl
    }
}

extern "C" void kernel_launch(void* const* d_in, const int* in_sizes, int n_in,
                              void* d_out, int out_size, void* d_ws, size_t ws_size,
                              hipStream_t stream) {
    const float* p0 = (const float*)d_in[0];
    const float* p1 = (const float*)d_in[1];
    const float* p2 = (const float*)d_in[2];
    const float* gtb = (const float*)d_in[3];
    const int* gtl = (const int*)d_in[4];
    float* out = (float*)d_out;

    char* w = (char*)d_ws;
    float* pred = (float*)w;                          // BN*4 floats (4.3 MB)
    float* lse = pred + (size_t)BN * 4;               // BN*4 floats (4.3 MB)
    float* thr = lse + (size_t)BN * 4;                // 1024
    float* posA = thr + NB * NG;                      // 1024
    float* posI = posA + NB * NG;                     // 1024
    unsigned* maskv = (unsigned*)(posI + NB * NG);    // BN (1.07 MB)
    int* matchedv = (int*)(maskv + BN);               // BN (1.07 MB)
    float* part_bce = (float*)(matchedv + BN);        // 4224 floats
    float* part_corr = part_bce + NBLK1;              // 1056
    float* part_liou = part_corr + NBLK3;             // 1056
    float* part_ldfl = part_liou + NBLK3;             // 1056
    unsigned* partN = (unsigned*)(part_ldfl + NBLK3); // 1056

    hipLaunchKernelGGL(k1_fused, dim3(NBLK1), dim3(256), 0, stream,
                       p0, p1, p2, pred, lse, part_bce, posA, posI);
    hipLaunchKernelGGL(k2_thr, dim3(NG, NB), dim3(256), 0, stream,
                       p0, p1, p2, gtb, gtl, pred, thr);
    hipLaunchKernelGGL(k3_mask, dim3(NBLKN, NB), dim3(256), 0, stream,
                       p0, p1, p2, thr, pred, gtb, gtl, maskv, matchedv, posA, posI, partN);
    hipLaunchKernelGGL(k5_loss, dim3(NBLKN, NB), dim3(256), 0, stream,
                       p0, p1, p2, maskv, matchedv, posA, posI, gtb, gtl, pred, lse,
                       part_corr, part_liou, part_ldfl);
    hipLaunchKernelGGL(k6_final, dim3(1), dim3(256), 0, stream,
                       part_bce, part_corr, part_liou, part_ldfl, partN, out);
}

// Round 7
// 249.485 us; speedup vs baseline: 1.1079x; 1.0721x over previous
//
#include <hip/hip_runtime.h>
#include <hip/hip_bf16.h>

// Problem constants
#define NB 32          // batch
#define NG 32          // max gts
#define NC 80          // classes
#define NTOT 8400      // 6400 + 1600 + 400
#define CH 144
#define BN (NB * NTOT)            // 268800 anchors total

#define TILES_PER_B 132           // 100 (l0) + 25 (l1) + 7 (l2, last partial=16)
#define NBLK1 (NB * TILES_PER_B)  // 4224
#define NBLKN 33                  // ceil(NTOT/256)
#define NBLK3 (NBLKN * NB)        // 1056

struct AInfo {
    const float* base;  // p[lvl] + b*144*hw  (channel-major)
    int hw;
    int off;
    float cx, cy, stride;
};

__device__ __forceinline__ AInfo anchor_info(int n, int b, const float* p0, const float* p1, const float* p2) {
    AInfo ai;
    if (n < 6400) {
        int x = n % 80, y = n / 80;
        ai.hw = 6400; ai.off = n;
        ai.cx = (x + 0.5f) * 8.0f; ai.cy = (y + 0.5f) * 8.0f; ai.stride = 8.0f;
        ai.base = p0 + (size_t)b * CH * 6400;
    } else if (n < 8000) {
        int m = n - 6400; int x = m % 40, y = m / 40;
        ai.hw = 1600; ai.off = m;
        ai.cx = (x + 0.5f) * 16.0f; ai.cy = (y + 0.5f) * 16.0f; ai.stride = 16.0f;
        ai.base = p1 + (size_t)b * CH * 1600;
    } else {
        int m = n - 8000; int x = m % 20, y = m / 20;
        ai.hw = 400; ai.off = m;
        ai.cx = (x + 0.5f) * 32.0f; ai.cy = (y + 0.5f) * 32.0f; ai.stride = 32.0f;
        ai.base = p2 + (size_t)b * CH * 400;
    }
    return ai;
}

__device__ __forceinline__ void ins10(float a[10], float v) {
    if (v > a[9]) {
        a[9] = v;
#pragma unroll
        for (int i = 8; i >= 0; i--) {
            if (a[i + 1] > a[i]) { float t = a[i]; a[i] = a[i + 1]; a[i + 1] = t; }
        }
    }
}

__device__ __forceinline__ float iou_fn(float4 gb, float4 pb, float ap) {
    float ag = fmaxf(gb.z - gb.x, 0.f) * fmaxf(gb.w - gb.y, 0.f);
    float iw = fmaxf(fminf(gb.z, pb.z) - fmaxf(gb.x, pb.x), 0.f);
    float ih = fmaxf(fminf(gb.w, pb.w) - fmaxf(gb.y, pb.y), 0.f);
    float inter = iw * ih;
    return inter / (ag + ap - inter + 1e-7f);
}

// align metric — same formula/op-order in k2, k3, k5 so recomputed values are bit-identical.
__device__ __forceinline__ float align_metric(float s, float iou) {
    float sg = 1.f / (1.f + __expf(-s));
    float i2 = iou * iou;
    return sqrtf(sg) * i2 * i2 * i2;
}

__device__ __forceinline__ float ciou_fn(float4 p, float4 t) {
    float w1 = p.z - p.x, h1 = p.w - p.y;
    float w2 = t.z - t.x, h2 = t.w - t.y;
    float iw = fmaxf(fminf(p.z, t.z) - fmaxf(p.x, t.x), 0.f);
    float ih = fmaxf(fminf(p.w, t.w) - fmaxf(p.y, t.y), 0.f);
    float inter = iw * ih;
    float un = w1 * h1 + w2 * h2 - inter + 1e-7f;
    float iou = inter / un;
    float cw = fmaxf(p.z, t.z) - fminf(p.x, t.x);
    float chh = fmaxf(p.w, t.w) - fminf(p.y, t.y);
    float c2 = cw * cw + chh * chh + 1e-7f;
    float dx = p.x + p.z - t.x - t.z, dy = p.y + p.w - t.y - t.w;
    float rho2 = (dx * dx + dy * dy) * 0.25f;
    float da = atanf(w2 / (h2 + 1e-7f)) - atanf(w1 / (h1 + 1e-7f));
    float v = 0.4052847345693511f * da * da;
    float al = v / (v - iou + 1.f + 1e-7f);
    return iou - rho2 / c2 - al * v;
}

// ---------------- K1: fused decode (DFL softmax -> pred/lse) + BCE base, one pass ----------------
__global__ __launch_bounds__(256) void k1_fused(
    const float* __restrict__ p0, const float* __restrict__ p1, const float* __restrict__ p2,
    float* __restrict__ pred, float* __restrict__ lse, float* __restrict__ part_bce,
    float* __restrict__ posA, float* __restrict__ posI) {
    int blk = blockIdx.x;
    if (blk == 0) {  // absorb k0: zero pos maxima (k3 consumes them after this kernel completes)
        for (int i = threadIdx.x; i < NB * NG; i += 256) { posA[i] = 0.f; posI[i] = 0.f; }
    }
    int b = blk / TILES_PER_B;
    int tile = blk - b * TILES_PER_B;
    const float* base; int hw, o0, lvl_off, W; float spx;
    if (tile < 100)      { base = p0; hw = 6400; o0 = tile * 64;          lvl_off = 0;    W = 80; spx = 8.f;  }
    else if (tile < 125) { base = p1; hw = 1600; o0 = (tile - 100) * 64;  lvl_off = 6400; W = 40; spx = 16.f; }
    else                 { base = p2; hw = 400;  o0 = (tile - 125) * 64;  lvl_off = 8000; W = 20; spx = 32.f; }
    base += (size_t)b * CH * hw;
    int valid = min(64, hw - o0);   // 64 or 16; always a multiple of 4

    // Phase A: DFL decode, thread = (local anchor, side); 16 independent loads batched
    int a = threadIdx.x >> 2, k = threadIdx.x & 3;
    if (a < valid) {
        const float* col = base + (size_t)(k * 16) * hw + o0 + a;
        float v[16]; float mx = -1e30f;
#pragma unroll
        for (int j = 0; j < 16; j++) v[j] = col[(size_t)j * hw];
#pragma unroll
        for (int j = 0; j < 16; j++) mx = fmaxf(mx, v[j]);
        float se = 0.f, we = 0.f;
#pragma unroll
        for (int j = 0; j < 16; j++) { float e = __expf(v[j] - mx); se += e; we += e * (float)j; }
        float dist = we / se * spx;
        float lv = mx + __logf(se);
        int nl = o0 + a;
        int x = nl % W, y = nl / W;
        float cx = (x + 0.5f) * spx, cy = (y + 0.5f) * spx;
        float c = (k & 1) ? cy : cx;
        size_t ai = (size_t)b * NTOT + lvl_off + nl;
        pred[ai * 4 + k] = (k < 2) ? (c - dist) : (c + dist);
        lse[ai * 4 + k] = lv;
    }

    // Phase B: BCE over 80 cls channels via float4 loads.
    // 80 channels x (valid/4) float4s; unit u = ch*16 + f4, 5 units/thread.
    int valid4 = valid >> 2;
    const float* clsb = base + (size_t)64 * hw + o0;
    float4 vv[5]; bool okf[5];
#pragma unroll
    for (int i = 0; i < 5; i++) {
        int u = threadIdx.x + 256 * i;
        int ch = u >> 4, f4 = u & 15;
        okf[i] = (f4 < valid4);
        if (okf[i]) vv[i] = ((const float4*)(clsb + (size_t)ch * hw))[f4];
    }
    float bce = 0.f;
#pragma unroll
    for (int i = 0; i < 5; i++) {
        if (okf[i]) {
            float s;
            s = vv[i].x; bce += fmaxf(s, 0.f) + __logf(1.f + __expf(-fabsf(s)));
            s = vv[i].y; bce += fmaxf(s, 0.f) + __logf(1.f + __expf(-fabsf(s)));
            s = vv[i].z; bce += fmaxf(s, 0.f) + __logf(1.f + __expf(-fabsf(s)));
            s = vv[i].w; bce += fmaxf(s, 0.f) + __logf(1.f + __expf(-fabsf(s)));
        }
    }
#pragma unroll
    for (int off = 32; off > 0; off >>= 1) bce += __shfl_xor(bce, off, 64);
    __shared__ float red[4];
    if ((threadIdx.x & 63) == 0) red[threadIdx.x >> 6] = bce;
    __syncthreads();
    if (threadIdx.x == 0)
        part_bce[blk] = red[0] + red[1] + red[2] + red[3];
}

// ---------------- K2: per (b,g) top-10 threshold — scan only the in-box sub-rectangles ----------------
// Anchors outside the gt box have align == 0 exactly; seeding the top-10 with 0.0 is exact
// because there are always >= 10 out-of-box anchors (8400 total, <= ~1000 in-box).
__global__ __launch_bounds__(256) void k2_thr(
    const float* __restrict__ p0, const float* __restrict__ p1, const float* __restrict__ p2,
    const float* __restrict__ gtb, const int* __restrict__ gtl,
    const float* __restrict__ pred, float* __restrict__ thr) {
    int g = blockIdx.x, b = blockIdx.y;
    const float* gb = gtb + (size_t)(b * NG + g) * 4;
    float gx1 = gb[0], gy1 = gb[1], gx2 = gb[2], gy2 = gb[3];
    bool vg = (gx1 + gy1 + gx2 + gy2) > 0.f;
    int label = gtl[b * NG + g];
    float4 gb4 = { gx1, gy1, gx2, gy2 };
    const float* bases[3] = { p0 + (size_t)b * CH * 6400,
                              p1 + (size_t)b * CH * 1600,
                              p2 + (size_t)b * CH * 400 };
    const int Ws[3] = { 80, 40, 20 }, hws[3] = { 6400, 1600, 400 }, loff[3] = { 0, 6400, 8000 };
    const float ss[3] = { 8.f, 16.f, 32.f };
    int X0[3], W_[3], Y0[3], CNT[3];
    int tot = 0;
#pragma unroll
    for (int l = 0; l < 3; l++) {
        int x0 = 0, x1 = -1, y0 = 0, y1 = -1;
        if (vg) {
            float s = ss[l];
            x0 = max(0, (int)floorf(gx1 / s - 0.5f));
            x1 = min(Ws[l] - 1, (int)floorf(gx2 / s - 0.5f) + 1);
            y0 = max(0, (int)floorf(gy1 / s - 0.5f));
            y1 = min(Ws[l] - 1, (int)floorf(gy2 / s - 0.5f) + 1);
        }
        int w = x1 - x0 + 1, h = y1 - y0 + 1;
        X0[l] = x0; Y0[l] = y0; W_[l] = w;
        CNT[l] = (w > 0 && h > 0) ? w * h : 0;
        tot += CNT[l];
    }
    float top[10];
#pragma unroll
    for (int i = 0; i < 10; i++) top[i] = 0.f;
    const float4* pred4 = (const float4*)pred + (size_t)b * NTOT;
    for (int i = threadIdx.x; i < tot; i += 256) {
        int l = 0, r = i;
        if (r >= CNT[0]) { r -= CNT[0]; l = 1; if (r >= CNT[1]) { r -= CNT[1]; l = 2; } }
        int w = W_[l];
        int y = Y0[l] + r / w, x = X0[l] + r % w;
        float s = ss[l];
        float cx = (x + 0.5f) * s, cy = (y + 0.5f) * s;
        int nr = y * Ws[l] + x;
        float4 pb = pred4[loff[l] + nr];
        float sc = bases[l][(size_t)(64 + label) * hws[l] + nr];
        float ap = fmaxf(pb.z - pb.x, 0.f) * fmaxf(pb.w - pb.y, 0.f);
        float iou = iou_fn(gb4, pb, ap);
        bool ing = (cx > gx1) && (cx < gx2) && (cy > gy1) && (cy < gy2);
        float al = 0.f;
        if (ing && vg) al = align_metric(sc, iou);
        ins10(top, al);
    }
    __shared__ float s_top[256 * 10];
#pragma unroll
    for (int i = 0; i < 10; i++) s_top[threadIdx.x * 10 + i] = top[i];
    __syncthreads();
    if (threadIdx.x < 64) {
        float mt[10];
#pragma unroll
        for (int i = 0; i < 10; i++) mt[i] = 0.f;
        for (int src = threadIdx.x; src < 256; src += 64)
#pragma unroll
            for (int i = 0; i < 10; i++) ins10(mt, s_top[src * 10 + i]);
        float thrv = 0.f;
        for (int r = 0; r < 10; r++) {
            unsigned long long key = ((unsigned long long)__float_as_uint(mt[0]) << 32) | (unsigned)threadIdx.x;
#pragma unroll
            for (int off = 32; off > 0; off >>= 1) {
                unsigned long long o = __shfl_xor(key, off, 64);
                if (o > key) key = o;
            }
            thrv = __uint_as_float((unsigned)(key >> 32));
            if ((key & 63ULL) == (unsigned long long)threadIdx.x) {
#pragma unroll
                for (int i = 0; i < 9; i++) mt[i] = mt[i + 1];
                mt[9] = 0.f;
            }
        }
        if (threadIdx.x == 0) thr[b * NG + g] = thrv;
    }
}

// ---------------- K3: per (b,n) mask, matched, pos maxima, num_pos partial ----------------
// Invalid gts are sanitized to sentinel boxes (in-box test false, iou exactly 0 — same as
// the reference's zero boxes). Per-g early-out: coordinate test + wave vote before any load.
__global__ __launch_bounds__(256) void k3_mask(
    const float* __restrict__ p0, const float* __restrict__ p1, const float* __restrict__ p2,
    const float* __restrict__ thr, const float* __restrict__ pred,
    const float* __restrict__ gtb, const int* __restrict__ gtl,
    unsigned* __restrict__ maskv, int* __restrict__ matchedv,
    float* __restrict__ posA, float* __restrict__ posI, unsigned* __restrict__ partN) {
    int b = blockIdx.y;
    int n = blockIdx.x * 256 + threadIdx.x;
    __shared__ float s_thr[NG];
    __shared__ float4 s_gt[NG];
    __shared__ int s_lab[NG];
    if (threadIdx.x < NG) {
        s_thr[threadIdx.x] = thr[b * NG + threadIdx.x];
        float4 gb4 = ((const float4*)gtb)[b * NG + threadIdx.x];
        if (!((gb4.x + gb4.y + gb4.z + gb4.w) > 0.f))
            gb4 = make_float4(1e30f, 1e30f, -1e30f, -1e30f);  // sentinel: ing=false, iou=0
        s_gt[threadIdx.x] = gb4;
        s_lab[threadIdx.x] = gtl[b * NG + threadIdx.x];
    }
    __syncthreads();
    bool fg = false;
    if (n < NTOT) {
        AInfo ai = anchor_info(n, b, p0, p1, p2);
        float4 pb = ((const float4*)pred)[(size_t)b * NTOT + n];
        float ap = fmaxf(pb.z - pb.x, 0.f) * fmaxf(pb.w - pb.y, 0.f);
        unsigned m = 0;
        for (int g = 0; g < NG; g++) {
            float4 gb4 = s_gt[g];
            bool ing = (ai.cx > gb4.x) && (ai.cx < gb4.z) && (ai.cy > gb4.y) && (ai.cy < gb4.w);
            if (__any(ing)) {
                float al = 0.f;
                if (ing) {
                    float iou = iou_fn(gb4, pb, ap);
                    float s = ai.base[(size_t)(64 + s_lab[g]) * ai.hw + ai.off];
                    al = align_metric(s, iou);
                }
                if (al >= s_thr[g] && al > 1e-9f) m |= (1u << g);
            }
        }
        int cnt = __popc(m);
        int matched = -1;
        if (cnt > 0) {
            if (cnt > 1) {
                float best = -1.f; int bg = 0;
                for (int g = 0; g < NG; g++) {
                    float iou = iou_fn(s_gt[g], pb, ap);
                    if (iou > best) { best = iou; bg = g; }
                }
                m = 1u << bg;  // best_oh replaces mask when multi
            }
            for (int g = 0; g < NG; g++) {
                if ((m >> g) & 1u) {
                    float4 gb4 = s_gt[g];
                    float iou = iou_fn(gb4, pb, ap);
                    bool ing = (ai.cx > gb4.x) && (ai.cx < gb4.z) && (ai.cy > gb4.y) && (ai.cy < gb4.w);
                    float al = 0.f;
                    if (ing) {
                        float s = ai.base[(size_t)(64 + s_lab[g]) * ai.hw + ai.off];
                        al = align_metric(s, iou);
                    }
                    atomicMax((int*)&posI[b * NG + g], __float_as_int(iou));
                    atomicMax((int*)&posA[b * NG + g], __float_as_int(al));
                }
            }
            matched = __ffs(m) - 1;
            fg = true;
        }
        maskv[(size_t)b * NTOT + n] = m;
        matchedv[(size_t)b * NTOT + n] = matched;
    }
    unsigned long long bal = __ballot(fg);
    __shared__ unsigned redN[4];
    if ((threadIdx.x & 63) == 0) redN[threadIdx.x >> 6] = (unsigned)__popcll(bal);
    __syncthreads();
    if (threadIdx.x == 0)
        partN[blockIdx.y * gridDim.x + blockIdx.x] = redN[0] + redN[1] + redN[2] + redN[3];
}

// ---------------- K5: fg losses (norm via recomputed align, bce-corr, ciou, dfl) ----------------
__global__ __launch_bounds__(256) void k5_loss(
    const float* __restrict__ p0, const float* __restrict__ p1, const float* __restrict__ p2,
    const unsigned* __restrict__ maskv, const int* __restrict__ matchedv,
    const float* __restrict__ posA, const float* __restrict__ posI,
    const float* __restrict__ gtb, const int* __restrict__ gtl,
    const float* __restrict__ pred, const float* __restrict__ lse,
    float* __restrict__ part_corr, float* __restrict__ part_liou, float* __restrict__ part_ldfl) {
    int b = blockIdx.y;
    int n = blockIdx.x * 256 + threadIdx.x;
    __shared__ float4 s_gt[NG];
    __shared__ int s_lab[NG];
    __shared__ float s_pa[NG], s_pi[NG];
    if (threadIdx.x < NG) {
        s_gt[threadIdx.x] = ((const float4*)gtb)[b * NG + threadIdx.x];
        s_lab[threadIdx.x] = gtl[b * NG + threadIdx.x];
        s_pa[threadIdx.x] = posA[b * NG + threadIdx.x];
        s_pi[threadIdx.x] = posI[b * NG + threadIdx.x];
    }
    __syncthreads();
    float corr = 0.f, liou = 0.f, ldfl = 0.f;
    if (n < NTOT) {
        int mt = matchedv[(size_t)b * NTOT + n];
        if (mt >= 0) {
            AInfo ai = anchor_info(n, b, p0, p1, p2);
            const float* base = ai.base + ai.off;
            float4 pb = ((const float4*)pred)[(size_t)b * NTOT + n];
            float ap = fmaxf(pb.z - pb.x, 0.f) * fmaxf(pb.w - pb.y, 0.f);
            unsigned m = maskv[(size_t)b * NTOT + n];
            float nrm = 0.f;
            unsigned mm = m;
            while (mm) {
                int g = __ffs(mm) - 1; mm &= mm - 1;
                float4 gb4 = s_gt[g];
                float iou = iou_fn(gb4, pb, ap);
                bool ing = (ai.cx > gb4.x) && (ai.cx < gb4.z) && (ai.cy > gb4.y) && (ai.cy < gb4.w);
                float al = 0.f;
                if (ing) {
                    float s = base[(size_t)(64 + s_lab[g]) * ai.hw];
                    al = align_metric(s, iou);
                }
                nrm = fmaxf(nrm, al * s_pi[g] / (s_pa[g] + 1e-9f));
            }
            float s = base[(size_t)(64 + s_lab[mt]) * ai.hw];
            corr = s * nrm;
            float4 tb = s_gt[mt];
            liou = 1.f - ciou_fn(pb, tb);
            float4 l4 = ((const float4*)lse)[(size_t)b * NTOT + n];
            float lv[4] = { l4.x, l4.y, l4.z, l4.w };
            float d[4] = { fmaxf(ai.cx - tb.x, 0.f), fmaxf(ai.cy - tb.y, 0.f),
                           fmaxf(tb.z - ai.cx, 0.f), fmaxf(tb.w - ai.cy, 0.f) };
            float Ls[8];
            int li4[4], ui4[4]; float afr4[4];
#pragma unroll
            for (int k = 0; k < 4; k++) {
                float tbk = fminf(d[k], 14.999999f);
                float lo = floorf(tbk);
                afr4[k] = tbk - lo;
                li4[k] = (int)lo;
                ui4[k] = min(li4[k] + 1, 15);
            }
#pragma unroll
            for (int k = 0; k < 4; k++) {
                Ls[k * 2]     = base[(size_t)(k * 16 + li4[k]) * ai.hw];
                Ls[k * 2 + 1] = base[(size_t)(k * 16 + ui4[k]) * ai.hw];
            }
#pragma unroll
            for (int k = 0; k < 4; k++)
                ldfl += lv[k] - ((1.f - afr4[k]) * Ls[k * 2] + afr4[k] * Ls[k * 2 + 1]);
        }
    }
#pragma unroll
    for (int off = 32; off > 0; off >>= 1) {
        corr += __shfl_xor(corr, off, 64);
        liou += __shfl_xor(liou, off, 64);
        ldfl += __shfl_xor(ldfl, off, 64);
    }
    __shared__ float rc[4], ri[4], rd[4];
    if ((threadIdx.x & 63) == 0) {
        int w = threadIdx.x >> 6;
        rc[w] = corr; ri[w] = liou; rd[w] = ldfl;
    }
    __syncthreads();
    if (threadIdx.x == 0) {
        int blk = blockIdx.y * gridDim.x + blockIdx.x;
        part_corr[blk] = rc[0] + rc[1] + rc[2] + rc[3];
        part_liou[blk] = ri[0] + ri[1] + ri[2] + ri[3];
        part_ldfl[blk] = rd[0] + rd[1] + rd[2] + rd[3];
    }
}

// ---------------- K6: final reduce in fp64 ----------------
__global__ __launch_bounds__(256) void k6_final(
    const float* __restrict__ part_bce, const float* __restrict__ part_corr,
    const float* __restrict__ part_liou, const float* __restrict__ part_ldfl,
    const unsigned* __restrict__ partN, float* __restrict__ out) {
    double bce = 0.0, corr = 0.0, liou = 0.0, ldfl = 0.0, np = 0.0;
    for (int i = threadIdx.x; i < NBLK1; i += 256) bce += (double)part_bce[i];
    for (int i = threadIdx.x; i < NBLK3; i += 256) {
        corr += (double)part_corr[i];
        liou += (double)part_liou[i];
        ldfl += (double)part_ldfl[i];
        np   += (double)partN[i];
    }
#pragma unroll
    for (int off = 32; off > 0; off >>= 1) {
        bce  += __shfl_xor(bce, off, 64);
        corr += __shfl_xor(corr, off, 64);
        liou += __shfl_xor(liou, off, 64);
        ldfl += __shfl_xor(ldfl, off, 64);
        np   += __shfl_xor(np, off, 64);
    }
    __shared__ double rb[4], rc[4], ri[4], rd[4], rn[4];
    if ((threadIdx.x & 63) == 0) {
        int w = threadIdx.x >> 6;
        rb[w] = bce; rc[w] = corr; ri[w] = liou; rd[w] = ldfl; rn[w] = np;
    }
    __syncthreads();
    if (threadIdx.x == 0) {
        bce  = rb[0] + rb[1] + rb[2] + rb[3];
        corr = rc[0] + rc[1] + rc[2] + rc[3];
        liou = ri[0] + ri[1] + ri[2] + ri[3];
        ldfl = rd[0] + rd[1] + rd[2] + rd[3];
        np   = rn[0] + rn[1] + rn[2] + rn[3];
        if (np < 1.0) np = 1.0;
        out[0] = (float)(7.5 * liou / np);            // W_IOU * loss_iou
        out[1] = (float)(0.5 * (bce - corr) / np);    // W_CLS * loss_cls
        out[2] = (float)(1.5 * ldfl / np);            // W_DFL * loss_dfl
    }
}

extern "C" void kernel_launch(void* const* d_in, const int* in_sizes, int n_in,
                              void* d_out, int out_size, void* d_ws, size_t ws_size,
                              hipStream_t stream) {
    const float* p0 = (const float*)d_in[0];
    const float* p1 = (const float*)d_in[1];
    const float* p2 = (const float*)d_in[2];
    const float* gtb = (const float*)d_in[3];
    const int* gtl = (const int*)d_in[4];
    float* out = (float*)d_out;

    char* w = (char*)d_ws;
    float* pred = (float*)w;                          // BN*4 floats (4.3 MB)
    float* lse = pred + (size_t)BN * 4;               // BN*4 floats (4.3 MB)
    float* thr = lse + (size_t)BN * 4;                // 1024
    float* posA = thr + NB * NG;                      // 1024
    float* posI = posA + NB * NG;                     // 1024
    unsigned* maskv = (unsigned*)(posI + NB * NG);    // BN (1.07 MB)
    int* matchedv = (int*)(maskv + BN);               // BN (1.07 MB)
    float* part_bce = (float*)(matchedv + BN);        // 4224 floats
    float* part_corr = part_bce + NBLK1;              // 1056
    float* part_liou = part_corr + NBLK3;             // 1056
    float* part_ldfl = part_liou + NBLK3;             // 1056
    unsigned* partN = (unsigned*)(part_ldfl + NBLK3); // 1056

    hipLaunchKernelGGL(k1_fused, dim3(NBLK1), dim3(256), 0, stream,
                       p0, p1, p2, pred, lse, part_bce, posA, posI);
    hipLaunchKernelGGL(k2_thr, dim3(NG, NB), dim3(256), 0, stream,
                       p0, p1, p2, gtb, gtl, pred, thr);
    hipLaunchKernelGGL(k3_mask, dim3(NBLKN, NB), dim3(256), 0, stream,
                       p0, p1, p2, thr, pred, gtb, gtl, maskv, matchedv, posA, posI, partN);
    hipLaunchKernelGGL(k5_loss, dim3(NBLKN, NB), dim3(256), 0, stream,
                       p0, p1, p2, maskv, matchedv, posA, posI, gtb, gtl, pred, lse,
                       part_corr, part_liou, part_ldfl);
    hipLaunchKernelGGL(k6_final, dim3(1), dim3(256), 0, stream,
                       part_bce, part_corr, part_liou, part_ldfl, partN, out);
}